// Round 8
// baseline (196.228 us; speedup 1.0000x reference)
//
#include <hip/hip_runtime.h>
#include <cmath>
#include <cstring>

#define NUM_S   64
#define IMG_H   256
#define IMG_W   256
#define HWSZ    (IMG_H*IMG_W)          // 65536
#define BATCH   2
#define NPIX    (BATCH*HWSZ)           // 131072
#define NEL     (BATCH*NUM_S*HWSZ)     // 8388608
#define NSLICE  (BATCH*NUM_S)          // 128
#define VALID   246
#define EPS_F   1e-20f
#define C1_F    1e-4f
#define C2_F    9e-4f
#define RS      264                    // V_lds row stride (halves); 132 dw = 4 mod 32
#define FS      (16*RS)                // field size in halves = 4224
// slot layout: [0,1024) scan L1 (l1x 0..511, l1p 512..1023), [1024,7168) ssim
#define NSLOT_SCAN 1024
#define NSLOT_ALL  7168
#define PTPAD   1024                   // 4 KB stagger between pt arrays (channel de-alias)

typedef __fp16 half8  __attribute__((ext_vector_type(8)));
typedef __fp16 fp16x2 __attribute__((ext_vector_type(2)));
using fragC = __attribute__((ext_vector_type(4))) float;  // 4 fp32

union H8 { half8 v; short s[8]; int i[4]; };
union PK { fp16x2 v; int i; };

__device__ inline fp16x2 pkrtz(float a, float b) {
    return __builtin_amdgcn_cvt_pkrtz(a, b);   // 1 instr packs 2 values
}
__device__ inline float frcp(float x)  { return __builtin_amdgcn_rcpf(x); }
__device__ inline float flog2(float x) { return __builtin_amdgcn_logf(x); }   // v_log_f32
__device__ inline float fexp2(float x) { return __builtin_amdgcn_exp2f(x); }  // v_exp_f32

// block-reduce a float and WRITE to a unique slot (no init needed, no atomics)
__device__ inline void block_reduce_slot(float v, float* slot) {
    __shared__ float sm[8];
    __syncthreads();
    #pragma unroll
    for (int off = 32; off; off >>= 1) v += __shfl_down(v, off, 64);
    int lane = threadIdx.x & 63, w = threadIdx.x >> 6;
    if (lane == 0) sm[w] = v;
    __syncthreads();
    if (threadIdx.x == 0) {
        float s = 0.f;
        int nw = blockDim.x >> 6;
        for (int i = 0; i < nw; ++i) s += sm[i];
        *slot = s;
    }
}

// shared SSIM stage-1 tail (R15 swapped-operand form): 5 MFMA -> pack -> b64 LDS
__device__ inline void ssim_core_store(const H8& fX, const H8& fY, const H8& band,
                                       short (*Vl)[FS], int ro) {
    const fragC zero = {0.f, 0.f, 0.f, 0.f};
    H8 fXX, fYY, fXY;
    fXX.v = fX.v * fX.v;                   // v_pk_mul_f16
    fYY.v = fY.v * fY.v;
    fXY.v = fX.v * fY.v;
    // swapped operands (R15): D^T — lane's 4 regs = 4 consecutive cols at row n
    fragC v0 = __builtin_amdgcn_mfma_f32_16x16x32_f16(fX.v,  band.v, zero, 0, 0, 0);
    fragC v1 = __builtin_amdgcn_mfma_f32_16x16x32_f16(fY.v,  band.v, zero, 0, 0, 0);
    fragC v2 = __builtin_amdgcn_mfma_f32_16x16x32_f16(fXX.v, band.v, zero, 0, 0, 0);
    fragC v3 = __builtin_amdgcn_mfma_f32_16x16x32_f16(fYY.v, band.v, zero, 0, 0, 0);
    fragC v4 = __builtin_amdgcn_mfma_f32_16x16x32_f16(fXY.v, band.v, zero, 0, 0, 0);
    PK pa, pb;
    pa.v = pkrtz(v0[0], v0[1]); pb.v = pkrtz(v0[2], v0[3]);
    *(int2*)&Vl[0][ro] = make_int2(pa.i, pb.i);
    pa.v = pkrtz(v1[0], v1[1]); pb.v = pkrtz(v1[2], v1[3]);
    *(int2*)&Vl[1][ro] = make_int2(pa.i, pb.i);
    pa.v = pkrtz(v2[0], v2[1]); pb.v = pkrtz(v2[2], v2[3]);
    *(int2*)&Vl[2][ro] = make_int2(pa.i, pb.i);
    pa.v = pkrtz(v3[0], v3[1]); pb.v = pkrtz(v3[2], v3[3]);
    *(int2*)&Vl[3][ro] = make_int2(pa.i, pb.i);
    pa.v = pkrtz(v4[0], v4[1]); pb.v = pkrtz(v4[2], v4[3]);
    *(int2*)&Vl[4][ro] = make_int2(pa.i, pb.i);
}

__device__ inline float ssim_stage2(short (*Vl)[FS], const H8& band,
                                    int r0, int wid, int q, int n) {
    const fragC zero = {0.f, 0.f, 0.f, 0.f};
    float lsum = 0.f;
    for (int it = 0; it < 4; ++it) {
        int c0 = (wid * 4 + it) * 16;
        int so = n * RS + c0 + q * 8;
        so = min(so, FS - 8);              // overreach only hits weight-zero k
        H8 a0, a1, a2, a3, a4;
        *(int4*)a0.i = *(const int4*)&Vl[0][so];
        *(int4*)a1.i = *(const int4*)&Vl[1][so];
        *(int4*)a2.i = *(const int4*)&Vl[2][so];
        *(int4*)a3.i = *(const int4*)&Vl[3][so];
        *(int4*)a4.i = *(const int4*)&Vl[4][so];
        fragC o0 = __builtin_amdgcn_mfma_f32_16x16x32_f16(a0.v, band.v, zero, 0, 0, 0);
        fragC o1 = __builtin_amdgcn_mfma_f32_16x16x32_f16(a1.v, band.v, zero, 0, 0, 0);
        fragC o2 = __builtin_amdgcn_mfma_f32_16x16x32_f16(a2.v, band.v, zero, 0, 0, 0);
        fragC o3 = __builtin_amdgcn_mfma_f32_16x16x32_f16(a3.v, band.v, zero, 0, 0, 0);
        fragC o4 = __builtin_amdgcn_mfma_f32_16x16x32_f16(a4.v, band.v, zero, 0, 0, 0);
        #pragma unroll
        for (int reg = 0; reg < 4; ++reg) {
            int r = r0 + q * 4 + reg;
            int c = c0 + n;
            if (r < VALID && c < VALID) {
                float m1 = o0[reg], m2 = o1[reg];
                float s11 = o2[reg] - m1 * m1;
                float s22 = o3[reg] - m2 * m2;
                float s12 = o4[reg] - m1 * m2;
                float nv = (2.f * m1 * m2 + C1_F) * (2.f * s12 + C2_F);
                float dv = (m1 * m1 + m2 * m2 + C1_F) * (s11 + s22 + C2_F);
                lsum += nv * frcp(dv);
            }
        }
    }
    return lsum;
}

// Kernel 1 (FUSED): bid 0..511 = proven scan chains (R14 structure), no pt0
// store. bid 512..2559 = SSIM pair-0 blocks from fp32 img/tgt, executing in
// the chains' latency shadow. R17 FIX: pair-0 dispatch->slice mapping was
// sy = bi>>4 (batch0 slices 0..63 THEN batch1 0..63) while fwd chains
// stream BOTH batches' slices 0->63 concurrently from t=0 — half the
// pair-0 blocks ran outside their data's L2/L3 window (R7: FETCH 153.5MB
// = +60MB re-fetch). New mapping s=bi>>5, batch=(bi>>4)&1: ascending
// dispatch covers slice 0..63 for both batches simultaneously, matching
// the chains' streaming front (bwd chains give a mirrored second window).
__global__ __launch_bounds__(256) void fused_kernel(
    const float* __restrict__ img, const float* __restrict__ tgt,
    const float* __restrict__ un,
    uint2* __restrict__ pt1, uint2* __restrict__ pt2,
    const int4* __restrict__ bandTbl, float* __restrict__ slots)
{
    __shared__ short Vl[5][FS];            // 42240 B (scan blocks just reserve it)
    int bid = blockIdx.x;

    if (bid < 512) {
        // ---- scan chains: float2, 2 px/thread, depth-4 prefetch ----
        const int HW2 = HWSZ / 2;               // 32768 float2 per slice
        int tid = bid * 256 + threadIdx.x;
        bool bwd = tid >= (NPIX / 2);           // 0..255 fwd, 256..511 bwd
        int p2 = bwd ? tid - NPIX / 2 : tid;
        int b   = p2 >> 15;
        int hw2 = p2 & (HW2 - 1);
        int idx  = b * (NUM_S * HW2) + hw2 + (bwd ? (NUM_S - 1) * HW2 : 0);
        int step = bwd ? -HW2 : HW2;
        const float2* __restrict__ img2 = (const float2*)img;
        const float2* __restrict__ tgt2 = (const float2*)tgt;
        const float2* __restrict__ un2  = (const float2*)un;
        uint2* __restrict__ pt = bwd ? pt2 : pt1;

        float num[2] = {0.f, 0.f}, den[2] = {0.f, 0.f};
        float tm[2] = {-INFINITY, -INFINITY};
        float l1x = 0.f, l1p = 0.f;

        float2 xb[4], ub[4], tb[4];
        #pragma unroll
        for (int j = 0; j < 4; ++j) {
            int id = idx + j * step;
            xb[j] = img2[id]; ub[j] = un2[id]; tb[j] = tgt2[id];
        }

        for (int i = 0; i < NUM_S; i += 4) {
            #pragma unroll
            for (int j = 0; j < 4; ++j) {        // j is compile-time constant
                float2 x = xb[j], u = ub[j], t = tb[j];
                if (i + j + 4 < NUM_S) {         // refill slot 4 slices ahead
                    int id = idx + 4 * step;
                    xb[j] = img2[id]; ub[j] = un2[id]; tb[j] = tgt2[id];
                }
                float xc[2] = {x.x, x.y}, uc[2] = {u.x, u.y}, tc[2] = {t.x, t.y};
                float p[2];
                #pragma unroll
                for (int c = 0; c < 2; ++c) {
                    // w = eps - ln(u+eps) > 0;  e = exp(2x) * w^-2
                    float w = fmaf(flog2(uc[c] + EPS_F), -0.6931471805599453f, EPS_F);
                    float r = frcp(w);
                    float e = fexp2(xc[c] * 2.8853900817779268f) * (r * r);
                    num[c] = fmaf(e, xc[c], num[c]);
                    den[c] += e;
                    p[c] = num[c] * frcp(den[c]);
                    tm[c] = fmaxf(tm[c], tc[c]);
                    if (!bwd) l1x += fabsf(xc[c] - tc[c]);
                    l1p += fabsf(p[c] - tm[c]);
                }
                PK k0, k1;
                k0.v = pkrtz(p[0], tm[0]); k1.v = pkrtz(p[1], tm[1]);
                pt[idx] = make_uint2((unsigned)k0.i, (unsigned)k1.i);
                idx += step;
            }
        }
        block_reduce_slot(bwd ? 0.f : l1x, &slots[bid]);
        block_reduce_slot(l1p, &slots[512 + bid]);
        return;
    }

    // ---- ssim pair-0 from fp32 img/tgt ----
    int bi   = bid - 512;
    // R17 slice-aligned mapping: s ascending for BOTH batches concurrently
    int bx    = bi & 15;                   // row band
    int batch = (bi >> 4) & 1;
    int s     = bi >> 5;                   // 0..63, tracks fwd chain front
    int sy    = batch * NUM_S + s;
    int base = sy * HWSZ;
    int r0   = bx * 16;
    int lane = threadIdx.x & 63;
    int wid  = threadIdx.x >> 6;           // 0..3
    int q    = lane >> 4;                  // 0..3
    int n    = lane & 15;

    H8 band;
    *(int4*)band.i = bandTbl[lane];        // g[(q*8+j)-n], zero outside

    // zero pad cols [256,264): 5 fields x 16 rows x 4 dwords = 320 dwords
    for (int d = threadIdx.x; d < 320; d += 256) {
        int f = d >> 6, rm = d & 63, r = rm >> 2, cc = rm & 3;
        ((int*)Vl)[f * 2112 + r * 132 + 128 + cc] = 0;
    }

    bool clampR = (r0 == 240);
    const float* __restrict__ pa = img + base;
    const float* __restrict__ pb = tgt + base;
    int rowbase = r0 + q * 8;
    #pragma unroll
    for (int it = 0; it < 4; ++it) {
        int colb = (wid * 4 + it) * 16 + n;
        float xv[8], yv[8];
        if (!clampR) {
            #pragma unroll
            for (int j = 0; j < 8; ++j) {
                xv[j] = pa[(rowbase + j) * IMG_W + colb];
                yv[j] = pb[(rowbase + j) * IMG_W + colb];
            }
        } else {
            #pragma unroll
            for (int j = 0; j < 8; ++j) {
                int rr = min(rowbase + j, IMG_H - 1);
                xv[j] = pa[rr * IMG_W + colb];
                yv[j] = pb[rr * IMG_W + colb];
            }
        }
        H8 fX, fY;
        #pragma unroll
        for (int j = 0; j < 4; ++j) {      // bit-identical to old pt0 pack
            PK ka, kb;
            ka.v = pkrtz(xv[2 * j], xv[2 * j + 1]); fX.i[j] = ka.i;
            kb.v = pkrtz(yv[2 * j], yv[2 * j + 1]); fY.i[j] = kb.i;
        }
        int ro = n * RS + (wid * 4 + it) * 16 + q * 4;
        ssim_core_store(fX, fY, band, Vl, ro);
    }
    __syncthreads();
    float lsum = ssim_stage2(Vl, band, r0, wid, q, n);
    block_reduce_slot(lsum, &slots[NSLOT_SCAN + sy * 16 + bx]);
}

// Kernel 2: SSIM pairs 1,2 from packed pt1/pt2 (R15 swapped-operand form,
// pad layout RS=264). Merge via v_perm_b32. Freshness remap kept (pair1
// written ascending -> read descending; pair2 written descending -> read
// ascending).
__global__ __launch_bounds__(256) void ssim_kernel(
    const unsigned* __restrict__ pt1, const unsigned* __restrict__ pt2,
    const int4* __restrict__ bandTbl, float* __restrict__ slots)
{
    __shared__ short Vl[5][FS];            // 42240 B
    int pair  = blockIdx.z + 1;            // 1 or 2
    int yy    = blockIdx.y;
    int bsel  = yy & 1, ss = yy >> 1;
    int sy    = bsel * NUM_S + ((pair == 2) ? ss : (NUM_S - 1 - ss));
    int base  = sy * HWSZ;
    int r0    = blockIdx.x * 16;
    int lane  = threadIdx.x & 63;
    int wid   = threadIdx.x >> 6;          // 0..3
    int q     = lane >> 4;                 // 0..3
    int n     = lane & 15;

    const unsigned* __restrict__ pp = (pair == 1 ? pt1 : pt2) + base;
    bool clampR = (r0 == 240);

    // ---- stage 1: all 32 loads + band load upfront ----
    unsigned ld[32];
    {
        int rowbase = r0 + q * 8;
        if (!clampR) {
            const unsigned* pb = pp + rowbase * IMG_W + n;
            #pragma unroll
            for (int it = 0; it < 4; ++it)
                #pragma unroll
                for (int j = 0; j < 8; ++j)
                    ld[it * 8 + j] = pb[j * IMG_W + (wid * 4 + it) * 16];
        } else {
            #pragma unroll
            for (int it = 0; it < 4; ++it)
                #pragma unroll
                for (int j = 0; j < 8; ++j) {
                    int rr = min(rowbase + j, IMG_H - 1);
                    ld[it * 8 + j] = pp[rr * IMG_W + (wid * 4 + it) * 16 + n];
                }
        }
    }
    H8 band;
    *(int4*)band.i = bandTbl[lane];

    // zero pad cols [256,264)
    for (int d = threadIdx.x; d < 320; d += 256) {
        int f = d >> 6, rm = d & 63, r = rm >> 2, cc = rm & 3;
        ((int*)Vl)[f * 2112 + r * 132 + 128 + cc] = 0;
    }

    #pragma unroll
    for (int it = 0; it < 4; ++it) {
        H8 fX, fY;
        #pragma unroll
        for (int j = 0; j < 4; ++j) {          // {a(lo), b(hi)} via v_perm_b32
            unsigned a = ld[it * 8 + 2 * j], b2 = ld[it * 8 + 2 * j + 1];
            fX.i[j] = (int)__builtin_amdgcn_perm(b2, a, 0x05040100u);
            fY.i[j] = (int)__builtin_amdgcn_perm(b2, a, 0x07060302u);
        }
        int ro = n * RS + (wid * 4 + it) * 16 + q * 4;
        ssim_core_store(fX, fY, band, Vl, ro);
    }
    __syncthreads();
    float lsum = ssim_stage2(Vl, band, r0, wid, q, n);
    block_reduce_slot(lsum,
        &slots[NSLOT_SCAN + pair * 2048 + blockIdx.y * 16 + blockIdx.x]);
}

__global__ void finalize_kernel(const float* __restrict__ slots,
                                float* __restrict__ out) {
    __shared__ double sa[4], sb[4];
    double a = 0.0, bsum = 0.0;
    for (int i = threadIdx.x; i < NSLOT_SCAN; i += 256) a += (double)slots[i];
    for (int i = NSLOT_SCAN + threadIdx.x; i < NSLOT_ALL; i += 256) bsum += (double)slots[i];
    #pragma unroll
    for (int off = 32; off; off >>= 1) {
        a    += __shfl_down(a, off, 64);
        bsum += __shfl_down(bsum, off, 64);
    }
    int lane = threadIdx.x & 63, w = threadIdx.x >> 6;
    if (lane == 0) { sa[w] = a; sb[w] = bsum; }
    __syncthreads();
    if (threadIdx.x == 0) {
        double A = sa[0] + sa[1] + sa[2] + sa[3];
        double B = sb[0] + sb[1] + sb[2] + sb[3];
        out[0] = (float)(3.0 + A / (double)NEL -
                         B / ((double)NSLICE * (double)VALID * (double)VALID));
    }
}

// host float -> fp16 bits, RNE (taps are normal-range)
static unsigned short f32_to_f16(float f) {
    unsigned u; memcpy(&u, &f, 4);
    unsigned s = (u >> 16) & 0x8000u;
    int e = (int)((u >> 23) & 0xff) - 127 + 15;
    unsigned m = u & 0x7fffffu;
    unsigned h = s | ((unsigned)e << 10) | (m >> 13);
    unsigned rem = m & 0x1fffu;
    if (rem > 0x1000u || (rem == 0x1000u && (h & 1))) h++;
    return (unsigned short)h;
}
static double f16_to_d(unsigned short h) {
    unsigned e = (h >> 10) & 0x1f, m = h & 0x3ffu;
    return ldexp((double)(m + 1024), (int)e - 25);
}

extern "C" void kernel_launch(void* const* d_in, const int* in_sizes, int n_in,
                              void* d_out, int out_size, void* d_ws, size_t ws_size,
                              hipStream_t stream) {
    const float* img = (const float*)d_in[0];
    const float* tgt = (const float*)d_in[1];
    const float* un  = (const float*)d_in[2];
    float* out = (float*)d_out;

    unsigned* pt1 = (unsigned*)d_ws;               // 33.5 MB each, staggered
    unsigned* pt2 = pt1 + NEL + PTPAD;             // +4 KB phase shift
    float* slots = (float*)(pt2 + NEL);            // 7168 floats, written not added
    unsigned short* bandTbl = (unsigned short*)(slots + NSLOT_ALL);  // 64x8 fp16

    // gaussian(11, 1.5) in double; renormalize so fp16 taps sum to ~1;
    // band table built HOST-side, 1 KB async upload (graph-capture safe).
    static unsigned short h_band[64 * 8];
    {
        double g[11], s = 0.0;
        unsigned short h[11];
        for (int i = 0; i < 11; ++i) { double d = i - 5; g[i] = exp(-d * d / 4.5); s += g[i]; }
        for (int i = 0; i < 11; ++i) g[i] /= s;
        for (int iter = 0; iter < 3; ++iter) {
            double sb = 0.0;
            for (int i = 0; i < 11; ++i) { h[i] = f32_to_f16((float)g[i]); sb += f16_to_d(h[i]); }
            for (int i = 0; i < 11; ++i) g[i] /= sb;
        }
        for (int lane = 0; lane < 64; ++lane) {
            int q = lane >> 4, n = lane & 15;
            for (int j = 0; j < 8; ++j) {
                int kk = q * 8 + j - n;
                h_band[lane * 8 + j] = (kk >= 0 && kk < 11) ? h[kk] : 0;
            }
        }
    }
    hipMemcpyAsync(bandTbl, h_band, sizeof(h_band), hipMemcpyHostToDevice, stream);

    fused_kernel<<<512 + 2048, 256, 0, stream>>>(img, tgt, un,
        (uint2*)pt1, (uint2*)pt2, (const int4*)bandTbl, slots);
    ssim_kernel<<<dim3(16, NSLICE, 2), 256, 0, stream>>>(pt1, pt2,
        (const int4*)bandTbl, slots);
    finalize_kernel<<<1, 256, 0, stream>>>(slots, out);
}

// Round 9
// 187.281 us; speedup vs baseline: 1.0478x; 1.0478x over previous
//
#include <hip/hip_runtime.h>
#include <cmath>
#include <cstring>

#define NUM_S   64
#define IMG_H   256
#define IMG_W   256
#define HWSZ    (IMG_H*IMG_W)          // 65536
#define BATCH   2
#define NPIX    (BATCH*HWSZ)           // 131072
#define NEL     (BATCH*NUM_S*HWSZ)     // 8388608
#define NSLICE  (BATCH*NUM_S)          // 128
#define VALID   246
#define EPS_F   1e-20f
#define C1_F    1e-4f
#define C2_F    9e-4f
#define RS      264                    // V_lds row stride (halves); 132 dw = 4 mod 32
#define FS      (16*RS)                // field size in halves = 4224
// slot layout: [0,1024) scan L1 (l1x 0..511, l1p 512..1023), [1024,7168) ssim
#define NSLOT_SCAN 1024
#define NSLOT_ALL  7168
#define PTPAD   1024                   // 4 KB stagger between pt arrays (channel de-alias)

typedef __fp16 half8  __attribute__((ext_vector_type(8)));
typedef __fp16 fp16x2 __attribute__((ext_vector_type(2)));
using fragC = __attribute__((ext_vector_type(4))) float;  // 4 fp32

union H8 { half8 v; short s[8]; int i[4]; };
union PK { fp16x2 v; int i; };

struct GH { short h[11]; };            // fp16 bits of gaussian taps (sum ~= 1)

__device__ inline fp16x2 pkrtz(float a, float b) {
    return __builtin_amdgcn_cvt_pkrtz(a, b);   // 1 instr packs 2 values
}
__device__ inline float frcp(float x)  { return __builtin_amdgcn_rcpf(x); }
__device__ inline float flog2(float x) { return __builtin_amdgcn_logf(x); }   // v_log_f32
__device__ inline float fexp2(float x) { return __builtin_amdgcn_exp2f(x); }  // v_exp_f32

// block-reduce a float and WRITE to a unique slot (no init needed, no atomics)
__device__ inline void block_reduce_slot(float v, float* slot) {
    __shared__ float sm[8];
    __syncthreads();
    #pragma unroll
    for (int off = 32; off; off >>= 1) v += __shfl_down(v, off, 64);
    int lane = threadIdx.x & 63, w = threadIdx.x >> 6;
    if (lane == 0) sm[w] = v;
    __syncthreads();
    if (threadIdx.x == 0) {
        float s = 0.f;
        int nw = blockDim.x >> 6;
        for (int i = 0; i < nw; ++i) s += sm[i];
        *slot = s;
    }
}

// Kernel 1: per-pixel softmax-prefix scan, float2 (2 px/thread), depth-4
// prefetch with COMPILE-TIME buffer indices. EXACT R6/R14 structure (session
// best: 57.8-58.6us, FETCH 92MB, 3.34 TB/s). Measured-worse alternatives,
// do NOT revisit: depth-8 (65.8us, body bloat), 1px scalar (73.5us, 2x VMEM
// instrs), NT stores (poison pt lines), dedicated pack blocks (FETCH+27MB,
// steal BW), fused pair-0 ssim in latency shadow (R7/R8: FETCH+60MB — L2
// streams evict in ~us, no temporal window exists at this working-set size).
// Emits packed fp16 dwords: pt0={img,tgt} (fwd only), pt1/pt2={p,cummax}.
// Builds the 64x8 ssim band table once (block 0; same-stream ordering makes
// it visible to ssim_kernel).
__global__ __launch_bounds__(256) void scan_kernel(
    const float* __restrict__ img, const float* __restrict__ tgt,
    const float* __restrict__ un,
    uint2* __restrict__ pt0, uint2* __restrict__ pt1, uint2* __restrict__ pt2,
    float* __restrict__ slots, GH gh, unsigned short* __restrict__ bandTbl)
{
    if (blockIdx.x == 0 && threadIdx.x < 64) {   // one-time band table build
        int q = threadIdx.x >> 4, n = threadIdx.x & 15;
        #pragma unroll
        for (int j = 0; j < 8; ++j) {
            int kk = q * 8 + j - n;
            short hv = 0;
            #pragma unroll
            for (int w = 0; w < 11; ++w) hv = (kk == w) ? gh.h[w] : hv;
            bandTbl[threadIdx.x * 8 + j] = (unsigned short)hv;
        }
    }

    const int HW2 = HWSZ / 2;               // 32768 float2 per slice
    int tid = blockIdx.x * 256 + threadIdx.x;
    bool bwd = tid >= (NPIX / 2);           // blocks 0..255 fwd, 256..511 bwd
    int p2 = bwd ? tid - NPIX / 2 : tid;
    int b   = p2 >> 15;
    int hw2 = p2 & (HW2 - 1);
    int idx  = b * (NUM_S * HW2) + hw2 + (bwd ? (NUM_S - 1) * HW2 : 0);
    int step = bwd ? -HW2 : HW2;
    const float2* __restrict__ img2 = (const float2*)img;
    const float2* __restrict__ tgt2 = (const float2*)tgt;
    const float2* __restrict__ un2  = (const float2*)un;

    float num[2] = {0.f, 0.f}, den[2] = {0.f, 0.f}, tm[2] = {-INFINITY, -INFINITY};
    float l1x = 0.f, l1p = 0.f;

    float2 xb[4], ub[4], tb[4];
    #pragma unroll
    for (int j = 0; j < 4; ++j) {
        int id = idx + j * step;
        xb[j] = img2[id]; ub[j] = un2[id]; tb[j] = tgt2[id];
    }

    for (int i = 0; i < NUM_S; i += 4) {
        #pragma unroll
        for (int j = 0; j < 4; ++j) {        // j is compile-time constant
            float2 x = xb[j], u = ub[j], t = tb[j];
            if (i + j + 4 < NUM_S) {         // refill slot 4 slices ahead
                int id = idx + 4 * step;
                xb[j] = img2[id]; ub[j] = un2[id]; tb[j] = tgt2[id];
            }
            float xc[2] = {x.x, x.y}, uc[2] = {u.x, u.y}, tc[2] = {t.x, t.y};
            float p[2];
            #pragma unroll
            for (int c = 0; c < 2; ++c) {
                // w = eps - ln(u+eps) > 0;  e = exp(2x) * w^-2
                float w = fmaf(flog2(uc[c] + EPS_F), -0.6931471805599453f, EPS_F);
                float r = frcp(w);
                float e = fexp2(xc[c] * 2.8853900817779268f) * (r * r);
                num[c] = fmaf(e, xc[c], num[c]);
                den[c] += e;
                p[c] = num[c] * frcp(den[c]);
                tm[c] = fmaxf(tm[c], tc[c]);
                if (!bwd) l1x += fabsf(xc[c] - tc[c]);
                l1p += fabsf(p[c] - tm[c]);
            }
            PK k0, k1;
            k0.v = pkrtz(p[0], tm[0]); k1.v = pkrtz(p[1], tm[1]);
            uint2 pv = make_uint2((unsigned)k0.i, (unsigned)k1.i);
            if (!bwd) {
                PK a0, a1;
                a0.v = pkrtz(xc[0], tc[0]); a1.v = pkrtz(xc[1], tc[1]);
                pt0[idx] = make_uint2((unsigned)a0.i, (unsigned)a1.i);
                pt1[idx] = pv;
            } else {
                pt2[idx] = pv;
            }
            idx += step;
        }
    }
    block_reduce_slot(bwd ? 0.f : l1x, &slots[blockIdx.x]);
    block_reduce_slot(l1p, &slots[512 + blockIdx.x]);
}

// Kernel 2: MFMA separable-Gaussian SSIM, fp16 fragments, unified packed
// path (pad layout RS=264 — empirically beats XOR-swizzle despite lower
// occupancy, R3). Stage-1 operand swap (R15, verified neutral-to-positive
// R6): mfma(fX, band) — A/B fragment layouts of 16x16x32_f16 are
// index-identical, so the transposed C-tile puts a lane's 4 regs on 4
// consecutive cols at row n: LDS epilogue = 2 pkrtz + 1 ds_write_b64 per
// field (conflict-free: banks (4n+2q) mod 32 = 4 accesses/bank).
// R18 micro-opt (only change vs R6): {a,b} merge via v_perm_b32 (2 instrs,
// bit-identical — ran 2 full passes in R7/R8 with absmax 0.0).
__global__ __launch_bounds__(256) void ssim_kernel(
    const unsigned* __restrict__ pt0, const unsigned* __restrict__ pt1,
    const unsigned* __restrict__ pt2,
    const int4* __restrict__ bandTbl, float* __restrict__ slots)
{
    __shared__ short Vl[5][FS];            // 42240 B
    int pair  = blockIdx.z;
    int yy    = blockIdx.y;
    int bsel  = yy & 1, ss = yy >> 1;      // freshness remap (R14)
    int sy    = bsel * NUM_S + ((pair == 2) ? ss : (NUM_S - 1 - ss));
    int base  = sy * HWSZ;
    int r0    = blockIdx.x * 16;
    int lane  = threadIdx.x & 63;
    int wid   = threadIdx.x >> 6;          // 0..3
    int q     = lane >> 4;                 // 0..3
    int n     = lane & 15;

    const unsigned* __restrict__ pp =
        (pair == 0 ? pt0 : (pair == 1 ? pt1 : pt2)) + base;
    bool clampR = (r0 == 240);
    const fragC zero = {0.f, 0.f, 0.f, 0.f};

    // ---- stage 1: all 32 loads + band load upfront, then setup ----
    unsigned ld[32];
    {
        int rowbase = r0 + q * 8;
        if (!clampR) {
            const unsigned* pb = pp + rowbase * IMG_W + n;
            #pragma unroll
            for (int it = 0; it < 4; ++it)
                #pragma unroll
                for (int j = 0; j < 8; ++j)
                    ld[it * 8 + j] = pb[j * IMG_W + (wid * 4 + it) * 16];
        } else {
            #pragma unroll
            for (int it = 0; it < 4; ++it)
                #pragma unroll
                for (int j = 0; j < 8; ++j) {
                    int rr = min(rowbase + j, IMG_H - 1);
                    ld[it * 8 + j] = pp[rr * IMG_W + (wid * 4 + it) * 16 + n];
                }
        }
    }
    // band fragment: g[(q*8+j)-n], zero outside — one 16B load from table
    H8 band;
    *(int4*)band.i = bandTbl[lane];

    // zero pad cols [256,264): 5 fields x 16 rows x 4 dwords = 320 dwords
    for (int d = threadIdx.x; d < 320; d += 256) {
        int f = d >> 6, rm = d & 63, r = rm >> 2, cc = rm & 3;
        ((int*)Vl)[f * 2112 + r * 132 + 128 + cc] = 0;
    }

    #pragma unroll
    for (int it = 0; it < 4; ++it) {
        H8 fX, fY, fXX, fYY, fXY;
        #pragma unroll
        for (int j = 0; j < 4; ++j) {          // {a(lo), b(hi)} via v_perm_b32
            unsigned a = ld[it * 8 + 2 * j], b2 = ld[it * 8 + 2 * j + 1];
            fX.i[j] = (int)__builtin_amdgcn_perm(b2, a, 0x05040100u);
            fY.i[j] = (int)__builtin_amdgcn_perm(b2, a, 0x07060302u);
        }
        fXX.v = fX.v * fX.v;                   // v_pk_mul_f16
        fYY.v = fY.v * fY.v;
        fXY.v = fX.v * fY.v;
        // swapped operands (R15): D^T — lane's 4 regs = 4 consecutive cols, row n
        fragC v0 = __builtin_amdgcn_mfma_f32_16x16x32_f16(fX.v,  band.v, zero, 0, 0, 0);
        fragC v1 = __builtin_amdgcn_mfma_f32_16x16x32_f16(fY.v,  band.v, zero, 0, 0, 0);
        fragC v2 = __builtin_amdgcn_mfma_f32_16x16x32_f16(fXX.v, band.v, zero, 0, 0, 0);
        fragC v3 = __builtin_amdgcn_mfma_f32_16x16x32_f16(fYY.v, band.v, zero, 0, 0, 0);
        fragC v4 = __builtin_amdgcn_mfma_f32_16x16x32_f16(fXY.v, band.v, zero, 0, 0, 0);
        int ro = n * RS + (wid * 4 + it) * 16 + q * 4;   // row=n, col base
        PK pa, pb;
        pa.v = pkrtz(v0[0], v0[1]); pb.v = pkrtz(v0[2], v0[3]);
        *(int2*)&Vl[0][ro] = make_int2(pa.i, pb.i);
        pa.v = pkrtz(v1[0], v1[1]); pb.v = pkrtz(v1[2], v1[3]);
        *(int2*)&Vl[1][ro] = make_int2(pa.i, pb.i);
        pa.v = pkrtz(v2[0], v2[1]); pb.v = pkrtz(v2[2], v2[3]);
        *(int2*)&Vl[2][ro] = make_int2(pa.i, pb.i);
        pa.v = pkrtz(v3[0], v3[1]); pb.v = pkrtz(v3[2], v3[3]);
        *(int2*)&Vl[3][ro] = make_int2(pa.i, pb.i);
        pa.v = pkrtz(v4[0], v4[1]); pb.v = pkrtz(v4[2], v4[3]);
        *(int2*)&Vl[4][ro] = make_int2(pa.i, pb.i);
    }
    __syncthreads();

    // ---- stage 2 + epilogue ----
    float lsum = 0.f;
    for (int it = 0; it < 4; ++it) {
        int c0 = (wid * 4 + it) * 16;
        int so = n * RS + c0 + q * 8;
        so = min(so, FS - 8);              // overreach only hits weight-zero k
        H8 a0, a1, a2, a3, a4;
        *(int4*)a0.i = *(const int4*)&Vl[0][so];
        *(int4*)a1.i = *(const int4*)&Vl[1][so];
        *(int4*)a2.i = *(const int4*)&Vl[2][so];
        *(int4*)a3.i = *(const int4*)&Vl[3][so];
        *(int4*)a4.i = *(const int4*)&Vl[4][so];
        fragC o0 = __builtin_amdgcn_mfma_f32_16x16x32_f16(a0.v, band.v, zero, 0, 0, 0);
        fragC o1 = __builtin_amdgcn_mfma_f32_16x16x32_f16(a1.v, band.v, zero, 0, 0, 0);
        fragC o2 = __builtin_amdgcn_mfma_f32_16x16x32_f16(a2.v, band.v, zero, 0, 0, 0);
        fragC o3 = __builtin_amdgcn_mfma_f32_16x16x32_f16(a3.v, band.v, zero, 0, 0, 0);
        fragC o4 = __builtin_amdgcn_mfma_f32_16x16x32_f16(a4.v, band.v, zero, 0, 0, 0);
        #pragma unroll
        for (int reg = 0; reg < 4; ++reg) {
            int r = r0 + q * 4 + reg;
            int c = c0 + n;
            if (r < VALID && c < VALID) {
                float m1 = o0[reg], m2 = o1[reg];
                float s11 = o2[reg] - m1 * m1;
                float s22 = o3[reg] - m2 * m2;
                float s12 = o4[reg] - m1 * m2;
                float nv = (2.f * m1 * m2 + C1_F) * (2.f * s12 + C2_F);
                float dv = (m1 * m1 + m2 * m2 + C1_F) * (s11 + s22 + C2_F);
                lsum += nv * frcp(dv);
            }
        }
    }
    block_reduce_slot(lsum,
        &slots[NSLOT_SCAN + pair * 2048 + blockIdx.y * 16 + blockIdx.x]);
}

__global__ void finalize_kernel(const float* __restrict__ slots,
                                float* __restrict__ out) {
    __shared__ double sa[4], sb[4];
    double a = 0.0, bsum = 0.0;
    for (int i = threadIdx.x; i < NSLOT_SCAN; i += 256) a += (double)slots[i];
    for (int i = NSLOT_SCAN + threadIdx.x; i < NSLOT_ALL; i += 256) bsum += (double)slots[i];
    #pragma unroll
    for (int off = 32; off; off >>= 1) {
        a    += __shfl_down(a, off, 64);
        bsum += __shfl_down(bsum, off, 64);
    }
    int lane = threadIdx.x & 63, w = threadIdx.x >> 6;
    if (lane == 0) { sa[w] = a; sb[w] = bsum; }
    __syncthreads();
    if (threadIdx.x == 0) {
        double A = sa[0] + sa[1] + sa[2] + sa[3];
        double B = sb[0] + sb[1] + sb[2] + sb[3];
        out[0] = (float)(3.0 + A / (double)NEL -
                         B / ((double)NSLICE * (double)VALID * (double)VALID));
    }
}

// host float -> fp16 bits, RNE (taps are normal-range)
static unsigned short f32_to_f16(float f) {
    unsigned u; memcpy(&u, &f, 4);
    unsigned s = (u >> 16) & 0x8000u;
    int e = (int)((u >> 23) & 0xff) - 127 + 15;
    unsigned m = u & 0x7fffffu;
    unsigned h = s | ((unsigned)e << 10) | (m >> 13);
    unsigned rem = m & 0x1fffu;
    if (rem > 0x1000u || (rem == 0x1000u && (h & 1))) h++;
    return (unsigned short)h;
}
static double f16_to_d(unsigned short h) {
    unsigned e = (h >> 10) & 0x1f, m = h & 0x3ffu;
    return ldexp((double)(m + 1024), (int)e - 25);
}

extern "C" void kernel_launch(void* const* d_in, const int* in_sizes, int n_in,
                              void* d_out, int out_size, void* d_ws, size_t ws_size,
                              hipStream_t stream) {
    const float* img = (const float*)d_in[0];
    const float* tgt = (const float*)d_in[1];
    const float* un  = (const float*)d_in[2];
    float* out = (float*)d_out;

    unsigned* pt0 = (unsigned*)d_ws;               // 33.5 MB each, staggered
    unsigned* pt1 = pt0 + NEL + PTPAD;             // +4 KB phase shift
    unsigned* pt2 = pt1 + NEL + PTPAD;
    float* slots = (float*)(pt2 + NEL);            // 7168 floats, written not added
    unsigned short* bandTbl = (unsigned short*)(slots + NSLOT_ALL);  // 64x8 fp16

    // gaussian(11, 1.5) in double; renormalize so fp16 taps sum to ~1
    GH gh;
    {
        double g[11], s = 0.0;
        for (int i = 0; i < 11; ++i) { double d = i - 5; g[i] = exp(-d * d / 4.5); s += g[i]; }
        for (int i = 0; i < 11; ++i) g[i] /= s;
        for (int iter = 0; iter < 3; ++iter) {
            double sb = 0.0;
            unsigned short h[11];
            for (int i = 0; i < 11; ++i) { h[i] = f32_to_f16((float)g[i]); sb += f16_to_d(h[i]); }
            for (int i = 0; i < 11; ++i) { g[i] /= sb; gh.h[i] = (short)h[i]; }
        }
    }

    scan_kernel<<<NPIX / 256, 256, 0, stream>>>(img, tgt, un,
        (uint2*)pt0, (uint2*)pt1, (uint2*)pt2, slots, gh, bandTbl);
    ssim_kernel<<<dim3(16, NSLICE, 3), 256, 0, stream>>>(pt0, pt1, pt2,
        (const int4*)bandTbl, slots);
    finalize_kernel<<<1, 256, 0, stream>>>(slots, out);
}